// Round 3
// baseline (457.707 us; speedup 1.0000x reference)
//
#include <hip/hip_runtime.h>
#include <hip/hip_bf16.h>

// GCNConv encoder (all fp32 per reference dtypes):
//   ei = concat(edge_index, y_edge_index); add self loops
//   deg[d] = count(dst==d) + 1 ; dinv = rsqrt(deg)
//   h = x @ W
//   out = segsum(h[src] * dinv[src]*dinv[dst], dst) + h[i]*dinv[i]^2 + b
//
// ws layout (floats): h[N*32] | deg[N]  => 33*N*4 B ~= 13.2 MB
// acc IS d_out (fp32 [N,32]): initialized with self-loop msg + bias, then edge atomics.

#define LATD 32
#define INCH 128

__global__ void init_deg_k(float* deg, int n) {
    int i = blockIdx.x * 256 + threadIdx.x;
    if (i < n) deg[i] = 1.0f;  // self-loop
}

__global__ void count_deg_k(const int* __restrict__ ei, const int* __restrict__ yei,
                            float* __restrict__ deg, int e1, int e2) {
    int e = blockIdx.x * 256 + threadIdx.x;
    if (e >= e1 + e2) return;
    int dst = (e < e1) ? ei[e1 + e] : yei[e2 + (e - e1)];
    atomicAdd(&deg[dst], 1.0f);
}

// h = x @ W : [n,128] @ [128,32] -> [n,32] fp32
__global__ __launch_bounds__(256) void gemm_xw_k(const float* __restrict__ x,
                                                 const float* __restrict__ W,
                                                 float* __restrict__ h, int n) {
    __shared__ float Wl[INCH][LATD];   // 16 KiB
    __shared__ float xs[8][INCH];      // 4 KiB
    int tid = threadIdx.x;
    for (int i = tid; i < INCH * LATD; i += 256)
        Wl[i / LATD][i % LATD] = W[i];
    int row0 = blockIdx.x * 8;
    // 8 rows * 128 cols = 1024 floats; 256 threads -> float4 each
    {
        const float4* xv = (const float4*)(x + (size_t)row0 * INCH);
        float4* xsv = (float4*)&xs[0][0];
        int nvec = ((n - row0) < 8 ? (n - row0) : 8) * (INCH / 4);
        if (tid < nvec) xsv[tid] = xv[tid];
    }
    __syncthreads();
    int r = tid >> 5, j = tid & 31;
    int gr = row0 + r;
    if (gr >= n) return;
    float s = 0.0f;
#pragma unroll
    for (int k = 0; k < INCH; ++k) s += xs[r][k] * Wl[k][j];
    h[gr * LATD + j] = s;
}

// deg -> dinv in place
__global__ void rsqrt_inplace_k(float* deg, int n) {
    int i = blockIdx.x * 256 + threadIdx.x;
    if (i < n) deg[i] = rsqrtf(deg[i]);
}

// out = h*dinv^2 + b   (self-loop message + bias)
__global__ void self_bias_k(const float* __restrict__ dinv,
                            const float* __restrict__ h,
                            const float* __restrict__ b,
                            float* __restrict__ out, int total) {
    int idx = blockIdx.x * 256 + threadIdx.x;
    if (idx >= total) return;
    int i = idx >> 5, j = idx & 31;
    float d = dinv[i];
    out[idx] = h[idx] * d * d + b[j];
}

// one thread per (edge, lane): out[dst][j] += h[src][j] * dinv[src]*dinv[dst]
__global__ void scatter_k(const int* __restrict__ ei, const int* __restrict__ yei,
                          const float* __restrict__ dinv,
                          const float* __restrict__ h,
                          float* __restrict__ out, int e1, int e2) {
    int idx = blockIdx.x * 256 + threadIdx.x;
    int etot = e1 + e2;
    int e = idx >> 5;
    if (e >= etot) return;
    int j = idx & 31;
    int src, dst;
    if (e < e1) { src = ei[e]; dst = ei[e1 + e]; }
    else        { int t = e - e1; src = yei[t]; dst = yei[e2 + t]; }
    float norm = dinv[src] * dinv[dst];
    atomicAdd(&out[dst * LATD + j], h[src * LATD + j] * norm);
}

extern "C" void kernel_launch(void* const* d_in, const int* in_sizes, int n_in,
                              void* d_out, int out_size, void* d_ws, size_t ws_size,
                              hipStream_t stream) {
    const float* x  = (const float*)d_in[0];
    const int* ei   = (const int*)d_in[1];
    const int* yei  = (const int*)d_in[2];
    const float* W  = (const float*)d_in[3];
    const float* b  = (const float*)d_in[4];
    float* out = (float*)d_out;

    int n  = in_sizes[0] / INCH;
    int e1 = in_sizes[1] / 2;
    int e2 = in_sizes[2] / 2;

    float* ws  = (float*)d_ws;
    float* h   = ws;                      // 32*n floats
    float* deg = ws + (size_t)n * LATD;   // n floats (becomes dinv in place)

    init_deg_k<<<(n + 255) / 256, 256, 0, stream>>>(deg, n);
    count_deg_k<<<(e1 + e2 + 255) / 256, 256, 0, stream>>>(ei, yei, deg, e1, e2);
    gemm_xw_k<<<(n + 7) / 8, 256, 0, stream>>>(x, W, h, n);
    rsqrt_inplace_k<<<(n + 255) / 256, 256, 0, stream>>>(deg, n);
    self_bias_k<<<(out_size + 255) / 256, 256, 0, stream>>>(deg, h, b, out, out_size);
    scatter_k<<<(((size_t)(e1 + e2) * LATD + 255) / 256), 256, 0, stream>>>(ei, yei, deg, h, out, e1, e2);
}